// Round 1
// baseline (9933.135 us; speedup 1.0000x reference)
//
#include <hip/hip_runtime.h>
#include <math.h>

// Problem constants (fixed by reference)
constexpr int T  = 128;
constexpr int B  = 512;
constexpr int H  = 256;
constexpr int M  = 64;
constexpr int MW = 32;    // memory slots per workgroup (2 WGs per batch element)
constexpr int RS = 260;   // LDS row stride in floats (pad 256->260, 16B aligned, breaks bank patterns)

// One persistent workgroup per (b, m-half). 256 threads = 4 waves.
// Thread tiling for the 32x256 = mem@U mini-GEMM per step:
//   wave w owns h in [w*64, w*64+64); within wave: tx=lane&7 -> 8 h cols, ty=lane>>3 -> 4 m rows.
// Memory state lives in LDS across all 128 time steps (no grid sync needed:
// each (m,b) evolves independently given sent@W / keys@sent which we compute locally).
__global__ __launch_bounds__(256, 2)
void dynmem_kernel(const float* __restrict__ stories,  // [T,B,H]
                   const float* __restrict__ mask,     // [T,B]
                   const float* __restrict__ keys,     // [M,H]
                   const float* __restrict__ U,        // [H,H]
                   const float* __restrict__ W,        // [H,H]
                   const float* __restrict__ V,        // [H,H]
                   const float* __restrict__ prelu_a,  // [H]
                   float* __restrict__ out)            // [M*B*H] memory ++ [T*M*B] gates
{
    __shared__ float mem_s[MW * RS];   // 33280 B
    __shared__ float sent_s[H];
    __shared__ float sw_s[H];
    __shared__ float g_s[MW];
    __shared__ float norm_s[4 * MW];   // per-wave partial sq-norms

    const int tid  = threadIdx.x;
    const int b    = blockIdx.x >> 1;
    const int mb   = (blockIdx.x & 1) * MW;  // global m base for this WG
    const int wave = tid >> 6;
    const int lane = tid & 63;
    const int tx   = lane & 7;
    const int ty   = lane >> 3;
    const int h0   = wave * 64 + tx * 8;     // this thread's 8 h-columns
    const int m0   = ty * 4;                 // this thread's 4 local m-rows

    // ---- init memory state = keys (broadcast over b), unnormalized per reference ----
    for (int idx = tid; idx < MW * H; idx += 256) {
        int m = idx >> 8, h = idx & 255;
        mem_s[m * RS + h] = keys[(mb + m) * H + h];
    }

    // per-thread PReLU slopes for its h columns
    float pa[8];
#pragma unroll
    for (int j = 0; j < 8; ++j) pa[j] = prelu_a[h0 + j];

    // ---- key_cand tile kc[i][j] = sum_k keys[mb+m0+i][k] * V[k][h0+j] (once; ~1 step of GEMM) ----
    float kc[4][8];
#pragma unroll
    for (int i = 0; i < 4; ++i)
#pragma unroll
        for (int j = 0; j < 8; ++j) kc[i][j] = 0.f;

    for (int k = 0; k < H; k += 4) {
        float vr[4][8];
#pragma unroll
        for (int r = 0; r < 4; ++r) {
            float4 u0 = *(const float4*)(V + (k + r) * H + h0);
            float4 u1 = *(const float4*)(V + (k + r) * H + h0 + 4);
            vr[r][0] = u0.x; vr[r][1] = u0.y; vr[r][2] = u0.z; vr[r][3] = u0.w;
            vr[r][4] = u1.x; vr[r][5] = u1.y; vr[r][6] = u1.z; vr[r][7] = u1.w;
        }
#pragma unroll
        for (int i = 0; i < 4; ++i) {
            float4 av = *(const float4*)(keys + (mb + m0 + i) * H + k);
            float a[4] = {av.x, av.y, av.z, av.w};
#pragma unroll
            for (int r = 0; r < 4; ++r)
#pragma unroll
                for (int j = 0; j < 8; ++j)
                    kc[i][j] = fmaf(a[r], vr[r][j], kc[i][j]);
        }
    }

    const size_t gate_base = (size_t)M * B * H;

    for (int t = 0; t < T; ++t) {
        // ---- load this step's sentence ----
        if (tid < 64) {
            float4 v = *(const float4*)(stories + ((size_t)t * B + b) * H + tid * 4);
            *(float4*)(&sent_s[tid * 4]) = v;
        }
        __syncthreads();  // SYNC1: sent ready; prev step's mem_s writes visible

        const float maskv = mask[t * B + b];

        // ---- phase A (reads only old mem_s) ----

        // sent @ W column tid (coalesced W reads across lanes)
        {
            float acc = 0.f;
#pragma unroll 4
            for (int k = 0; k < H; ++k)
                acc = fmaf(sent_s[k], W[k * H + tid], acc);
            sw_s[tid] = acc;
        }

        // gate logit: dot(mem+keys, sent) per m; 8 lanes per m, interleaved k partition
        {
            int ml = tid >> 3, p = tid & 7;
            const float* kr = keys + (size_t)(mb + ml) * H;
            const float* mr = mem_s + ml * RS;
            float acc = 0.f;
#pragma unroll 8
            for (int i = 0; i < 32; ++i) {
                int k = p + 8 * i;
                acc = fmaf(kr[k] + mr[k], sent_s[k], acc);
            }
            acc += __shfl_xor(acc, 1);
            acc += __shfl_xor(acc, 2);
            acc += __shfl_xor(acc, 4);
            if (p == 0) {
                float g = 1.f / (1.f + expf(-acc));
                g_s[ml] = g;
                out[gate_base + (size_t)t * M * B + (size_t)(mb + ml) * B + b] = g;
            }
        }

        // mini-GEMM: acc[i][j] = sum_k mem_s[m0+i][k] * U[k][h0+j]
        float acc[4][8];
#pragma unroll
        for (int i = 0; i < 4; ++i)
#pragma unroll
            for (int j = 0; j < 8; ++j) acc[i][j] = 0.f;

        for (int k = 0; k < H; k += 4) {
            float ur[4][8];
#pragma unroll
            for (int r = 0; r < 4; ++r) {
                float4 u0 = *(const float4*)(U + (k + r) * H + h0);
                float4 u1 = *(const float4*)(U + (k + r) * H + h0 + 4);
                ur[r][0] = u0.x; ur[r][1] = u0.y; ur[r][2] = u0.z; ur[r][3] = u0.w;
                ur[r][4] = u1.x; ur[r][5] = u1.y; ur[r][6] = u1.z; ur[r][7] = u1.w;
            }
#pragma unroll
            for (int i = 0; i < 4; ++i) {
                float4 av = *(const float4*)(mem_s + (m0 + i) * RS + k);
                float a[4] = {av.x, av.y, av.z, av.w};
#pragma unroll
                for (int r = 0; r < 4; ++r)
#pragma unroll
                    for (int j = 0; j < 8; ++j)
                        acc[i][j] = fmaf(a[r], ur[r][j], acc[i][j]);
            }
        }

        __syncthreads();  // SYNC2: all reads of old mem_s done; sw_s/g_s ready

        // ---- phase B: candidate, update, normalize (each thread owns its (m,h) tile) ----
        float sw[8];
#pragma unroll
        for (int j = 0; j < 8; ++j) sw[j] = sw_s[h0 + j];

        float ps[4];
#pragma unroll
        for (int i = 0; i < 4; ++i) {
            float g = g_s[m0 + i] * maskv;
            float4 o0 = *(const float4*)(mem_s + (m0 + i) * RS + h0);
            float4 o1 = *(const float4*)(mem_s + (m0 + i) * RS + h0 + 4);
            float oldv[8] = {o0.x, o0.y, o0.z, o0.w, o1.x, o1.y, o1.z, o1.w};
            ps[i] = 0.f;
#pragma unroll
            for (int j = 0; j < 8; ++j) {
                float x = acc[i][j] + kc[i][j] + sw[j];
                float c = (x >= 0.f) ? x : pa[j] * x;
                float n = fmaf(g, c, oldv[j]);
                acc[i][j] = n;            // reuse acc as the new (unscaled) value
                ps[i] = fmaf(n, n, ps[i]);
            }
        }
        // reduce squared norms over the 8 tx lanes (within wave), then across waves via LDS
#pragma unroll
        for (int i = 0; i < 4; ++i) {
            ps[i] += __shfl_xor(ps[i], 1);
            ps[i] += __shfl_xor(ps[i], 2);
            ps[i] += __shfl_xor(ps[i], 4);
        }
        if (tx == 0) {
#pragma unroll
            for (int i = 0; i < 4; ++i) norm_s[wave * MW + m0 + i] = ps[i];
        }
        __syncthreads();  // SYNC3: norm partials visible

#pragma unroll
        for (int i = 0; i < 4; ++i) {
            int m = m0 + i;
            float s2 = norm_s[0 * MW + m] + norm_s[1 * MW + m]
                     + norm_s[2 * MW + m] + norm_s[3 * MW + m];
            float scale = 1.f / fmaxf(sqrtf(s2), 1e-12f);
            float4 n0, n1;
            n0.x = acc[i][0] * scale; n0.y = acc[i][1] * scale;
            n0.z = acc[i][2] * scale; n0.w = acc[i][3] * scale;
            n1.x = acc[i][4] * scale; n1.y = acc[i][5] * scale;
            n1.z = acc[i][6] * scale; n1.w = acc[i][7] * scale;
            *(float4*)(mem_s + m * RS + h0)     = n0;
            *(float4*)(mem_s + m * RS + h0 + 4) = n1;
        }
        // loop-top SYNC1 of next iteration orders these writes before next reads
    }

    __syncthreads();
    // ---- write final memory [M,B,H] (this WG's 32 rows, coalesced 1KB per row) ----
    for (int idx = tid; idx < MW * H; idx += 256) {
        int m = idx >> 8, h = idx & 255;
        out[((size_t)(mb + m) * B + b) * H + h] = mem_s[m * RS + h];
    }
}

extern "C" void kernel_launch(void* const* d_in, const int* in_sizes, int n_in,
                              void* d_out, int out_size, void* d_ws, size_t ws_size,
                              hipStream_t stream) {
    const float* stories = (const float*)d_in[0];
    const float* mask    = (const float*)d_in[1];
    const float* keys    = (const float*)d_in[2];
    const float* U       = (const float*)d_in[3];
    const float* W       = (const float*)d_in[4];
    const float* V       = (const float*)d_in[5];
    const float* prelu_a = (const float*)d_in[6];
    float* out = (float*)d_out;

    dynmem_kernel<<<dim3(B * 2), dim3(256), 0, stream>>>(
        stories, mask, keys, U, W, V, prelu_a, out);
}

// Round 2
// 6228.458 us; speedup vs baseline: 1.5948x; 1.5948x over previous
//
#include <hip/hip_runtime.h>
#include <math.h>

// Problem constants (fixed by reference)
constexpr int T  = 128;
constexpr int B  = 512;
constexpr int Hd = 256;
constexpr int M  = 64;

// ---- MFMA frag types (gfx950 mfma_f32_16x16x32_bf16: A/B = 8 bf16, C/D = 4 f32) ----
typedef __attribute__((ext_vector_type(8))) short  short8;
typedef __attribute__((ext_vector_type(4))) float  f32x4;
typedef __attribute__((ext_vector_type(4))) unsigned int u32x4;

union FragAB { u32x4 u; short8 s; };

// round-to-nearest-even bf16 split: v = hi + lo, both representable in bf16.
__device__ __forceinline__ unsigned int rne_bump(unsigned int u) {
    return u + 0x7FFFu + ((u >> 16) & 1u);
}
__device__ __forceinline__ unsigned int packbf(float v) {
    unsigned int u  = __builtin_bit_cast(unsigned int, v);
    unsigned int hi = rne_bump(u) & 0xFFFF0000u;          // bf16(v) in high half
    float hif = __builtin_bit_cast(float, hi);
    float lof = v - hif;
    unsigned int ul = __builtin_bit_cast(unsigned int, lof);
    unsigned int lo = rne_bump(ul) >> 16;                 // bf16(v - hi)
    return hi | lo;                                        // (hi16<<16)|lo16
}
__device__ __forceinline__ void splitbf(float v, unsigned short& h, unsigned short& l) {
    unsigned int p = packbf(v);
    h = (unsigned short)(p >> 16);
    l = (unsigned short)(p & 0xFFFFu);
}

// ---------------- prep kernels (loop-invariant work, into d_ws) ----------------

// SW[t*B+b][h] = sum_k stories[t*B+b][k] * W[k][h]   ([65536,256]@[256,256] f32)
__global__ __launch_bounds__(256) void k_sw(const float* __restrict__ S,
                                            const float* __restrict__ W,
                                            float* __restrict__ SWo) {
    const int tid  = threadIdx.x;
    const int wave = tid >> 6, lane = tid & 63, tx = lane & 7, ty = lane >> 3;
    const int r0 = blockIdx.x * 32 + ty * 4;
    const int h0 = wave * 64 + tx * 8;
    float acc[4][8];
#pragma unroll
    for (int i = 0; i < 4; ++i)
#pragma unroll
        for (int j = 0; j < 8; ++j) acc[i][j] = 0.f;
    for (int k = 0; k < 256; k += 4) {
        float wr[4][8];
#pragma unroll
        for (int rr = 0; rr < 4; ++rr) {
            float4 u0 = *(const float4*)(W + (k + rr) * 256 + h0);
            float4 u1 = *(const float4*)(W + (k + rr) * 256 + h0 + 4);
            wr[rr][0]=u0.x; wr[rr][1]=u0.y; wr[rr][2]=u0.z; wr[rr][3]=u0.w;
            wr[rr][4]=u1.x; wr[rr][5]=u1.y; wr[rr][6]=u1.z; wr[rr][7]=u1.w;
        }
#pragma unroll
        for (int i = 0; i < 4; ++i) {
            float4 av = *(const float4*)(S + (size_t)(r0 + i) * 256 + k);
            float a[4] = {av.x, av.y, av.z, av.w};
#pragma unroll
            for (int rr = 0; rr < 4; ++rr)
#pragma unroll
                for (int j = 0; j < 8; ++j)
                    acc[i][j] = fmaf(a[rr], wr[rr][j], acc[i][j]);
        }
    }
#pragma unroll
    for (int i = 0; i < 4; ++i) {
        float4 o0 = {acc[i][0], acc[i][1], acc[i][2], acc[i][3]};
        float4 o1 = {acc[i][4], acc[i][5], acc[i][6], acc[i][7]};
        *(float4*)(SWo + (size_t)(r0 + i) * 256 + h0)     = o0;
        *(float4*)(SWo + (size_t)(r0 + i) * 256 + h0 + 4) = o1;
    }
}

// KS[t*B+b][m] = keys[m] . stories[t*B+b]
__global__ __launch_bounds__(256) void k_ks(const float* __restrict__ S,
                                            const float* __restrict__ keys,
                                            float* __restrict__ KSo) {
    __shared__ float sent[256];
    const int tid = threadIdx.x;
    if (tid < 64)
        *(float4*)(sent + tid * 4) = *(const float4*)(S + (size_t)blockIdx.x * 256 + tid * 4);
    __syncthreads();
    const int m = tid >> 2, p = tid & 3;
    const float* kr = keys + m * 256 + p * 64;
    const float* sr = sent + p * 64;
    float a = 0.f;
#pragma unroll 8
    for (int i = 0; i < 64; ++i) a = fmaf(kr[i], sr[i], a);
    a += __shfl_xor(a, 1);
    a += __shfl_xor(a, 2);
    if (p == 0) KSo[(size_t)blockIdx.x * 64 + m] = a;
}

// KC[m][h] = keys[m] @ V[:,h]
__global__ __launch_bounds__(256) void k_kc(const float* __restrict__ keys,
                                            const float* __restrict__ V,
                                            float* __restrict__ KCo) {
    const int m = blockIdx.x, h = threadIdx.x;
    float a = 0.f;
#pragma unroll 4
    for (int k = 0; k < 256; ++k) a = fmaf(keys[m * 256 + k], V[k * 256 + h], a);
    KCo[m * 256 + h] = a;
}

// Fragment-reorder U (hi/lo bf16) into B-operand order, and build the KC ext tiles.
// UB layout: [kt(8)][ht(16)][lane(64)][j(8)]; lane gives k=kt*32+(l>>4)*8+j, h=ht*16+(l&15).
// KCfrag: [mt(4)][ht(16)][lane][j]; B_ext[k'][h] = (k'<16) ? KC[mt*16+k'][h] : 0.
__global__ __launch_bounds__(256) void k_frag(const float* __restrict__ U,
                                              const float* __restrict__ KC,
                                              unsigned short* __restrict__ UBhi,
                                              unsigned short* __restrict__ UBlo,
                                              unsigned short* __restrict__ KChi,
                                              unsigned short* __restrict__ KClo) {
    const int idx = blockIdx.x * 256 + threadIdx.x;   // [0, 65536)
    const int j = idx & 7, l = (idx >> 3) & 63, ht = (idx >> 9) & 15, top = idx >> 13;
    const int q = l >> 4, n = l & 15;
    const int k = top * 32 + q * 8 + j, h = ht * 16 + n;
    unsigned short hh, ll;
    splitbf(U[k * 256 + h], hh, ll);
    UBhi[idx] = hh; UBlo[idx] = ll;
    if (top < 4) {
        const int kp = q * 8 + j;
        float v = (kp < 16) ? KC[(top * 16 + kp) * 256 + h] : 0.f;
        splitbf(v, hh, ll);
        KChi[idx] = hh; KClo[idx] = ll;
    }
}

// ---------------- main recurrent kernel ----------------
// One wave per (b, 16-m tile): grid 2048 x 64 threads. No __syncthreads in the t-loop:
// the A-operand LDS tile is wave-private; gate/norm reduce within quads via shfl.
// State (f32) stays in registers; LDS holds bf16 hi/lo pairs (packed u32) of the state
// as the MFMA A-operand. GEMM = bf16x3 split (hi*hi + hi*lo + lo*hi), f32 accumulate.
// A row stride 268 u32: frag ds_read_b128 -> 8 distinct 4-bank groups (conflict-free);
// epilogue ds_write_b32 -> 2 lanes/bank (free per m136).
__global__ __launch_bounds__(64, 2)
void dynmem_main(const float* __restrict__ stories, const float* __restrict__ mask,
                 const float* __restrict__ keys, const float* __restrict__ prelu_a,
                 const float* __restrict__ SW, const float* __restrict__ KS,
                 const unsigned short* __restrict__ UBhi, const unsigned short* __restrict__ UBlo,
                 const unsigned short* __restrict__ KChi, const unsigned short* __restrict__ KClo,
                 float* __restrict__ out) {
    __shared__ __align__(16) unsigned int Ap[16 * 268];

    const int l = threadIdx.x;
    const int q = l >> 4, col = l & 15;       // col = C-col = B-n = A-row (per lane role)
    const int b  = blockIdx.x >> 2;
    const int mt = blockIdx.x & 3;
    const int m0 = mt * 16;
    const int rowl = q * 4;                   // local m row base this lane updates

    float pa_l[16];
    float old_[16][4];                        // [ht][r] : m = m0+rowl+r, h = ht*16+col
#pragma unroll
    for (int ht = 0; ht < 16; ++ht) pa_l[ht] = prelu_a[ht * 16 + col];
#pragma unroll
    for (int ht = 0; ht < 16; ++ht)
#pragma unroll
        for (int r = 0; r < 4; ++r)
            old_[ht][r] = keys[(m0 + rowl + r) * Hd + ht * 16 + col];
    // initial A tile = keys (unnormalized, per reference init)
#pragma unroll
    for (int ht = 0; ht < 16; ++ht)
#pragma unroll
        for (int r = 0; r < 4; ++r)
            Ap[(rowl + r) * 268 + ht * 16 + col] = packbf(old_[ht][r]);

    // identity A-fragment for the KC extension tile: A_I[m][k'] = (k'==m)
    FragAB fI;
#pragma unroll
    for (int jj = 0; jj < 4; ++jj) {
        unsigned int lo16 = (q * 8 + 2 * jj     == col) ? 0x3F80u : 0u;
        unsigned int hi16 = (q * 8 + 2 * jj + 1 == col) ? 0x3F80u : 0u;
        fI.u[jj] = lo16 | (hi16 << 16);
    }

    const size_t gbase = (size_t)M * B * Hd;

    for (int t = 0; t < T; ++t) {
        // ---- issue this step's small loads first (consumed after the MFMA block) ----
        const float* srow = stories + ((size_t)t * B + b) * Hd;
        const float* wrow = SW + ((size_t)t * B + b) * Hd;
        float sent_l[16], sw_l[16], ks_l[4];
#pragma unroll
        for (int ht = 0; ht < 16; ++ht) {
            sent_l[ht] = srow[ht * 16 + col];
            sw_l[ht]   = wrow[ht * 16 + col];
        }
#pragma unroll
        for (int r = 0; r < 4; ++r) ks_l[r] = KS[((size_t)t * B + b) * 64 + m0 + rowl + r];
        const float mv = mask[t * B + b];

        // ---- MFMA: acc[ht] = mem @ U (bf16x3) ----
        f32x4 acc[16];
#pragma unroll
        for (int ht = 0; ht < 16; ++ht) acc[ht] = (f32x4)(0.f);

#pragma unroll 1
        for (int kt = 0; kt < 8; ++kt) {
            const u32x4 p01 = *(const u32x4*)(Ap + col * 268 + kt * 32 + q * 8);
            const u32x4 p23 = *(const u32x4*)(Ap + col * 268 + kt * 32 + q * 8 + 4);
            FragAB ah, al;
            ah.u[0] = __builtin_amdgcn_perm(p01.y, p01.x, 0x07060302u);
            al.u[0] = __builtin_amdgcn_perm(p01.y, p01.x, 0x05040100u);
            ah.u[1] = __builtin_amdgcn_perm(p01.w, p01.z, 0x07060302u);
            al.u[1] = __builtin_amdgcn_perm(p01.w, p01.z, 0x05040100u);
            ah.u[2] = __builtin_amdgcn_perm(p23.y, p23.x, 0x07060302u);
            al.u[2] = __builtin_amdgcn_perm(p23.y, p23.x, 0x05040100u);
            ah.u[3] = __builtin_amdgcn_perm(p23.w, p23.z, 0x07060302u);
            al.u[3] = __builtin_amdgcn_perm(p23.w, p23.z, 0x05040100u);

            const unsigned short* bh = UBhi + ((size_t)kt * 16 * 64 + l) * 8;
            const unsigned short* bl = UBlo + ((size_t)kt * 16 * 64 + l) * 8;
#pragma unroll
            for (int ht = 0; ht < 16; ++ht) {
                FragAB fbh, fbl;
                fbh.u = *(const u32x4*)(bh + ht * 512);
                fbl.u = *(const u32x4*)(bl + ht * 512);
                acc[ht] = __builtin_amdgcn_mfma_f32_16x16x32_bf16(ah.s, fbh.s, acc[ht], 0, 0, 0);
                acc[ht] = __builtin_amdgcn_mfma_f32_16x16x32_bf16(ah.s, fbl.s, acc[ht], 0, 0, 0);
                acc[ht] = __builtin_amdgcn_mfma_f32_16x16x32_bf16(al.s, fbh.s, acc[ht], 0, 0, 0);
            }
        }
        // KC extension tile: D += I . KC_w  (adds keys@V bias, no registers/LDS needed)
        {
            const unsigned short* kh = KChi + ((size_t)mt * 16 * 64 + l) * 8;
            const unsigned short* kl = KClo + ((size_t)mt * 16 * 64 + l) * 8;
#pragma unroll
            for (int ht = 0; ht < 16; ++ht) {
                FragAB fbh, fbl;
                fbh.u = *(const u32x4*)(kh + ht * 512);
                fbl.u = *(const u32x4*)(kl + ht * 512);
                acc[ht] = __builtin_amdgcn_mfma_f32_16x16x32_bf16(fI.s, fbh.s, acc[ht], 0, 0, 0);
                acc[ht] = __builtin_amdgcn_mfma_f32_16x16x32_bf16(fI.s, fbl.s, acc[ht], 0, 0, 0);
            }
        }

        // ---- gate: sigmoid(old.sent + keys.sent) ; quad shfl-reduce over 16 cols ----
        float gd[4] = {0.f, 0.f, 0.f, 0.f};
#pragma unroll
        for (int ht = 0; ht < 16; ++ht)
#pragma unroll
            for (int r = 0; r < 4; ++r) gd[r] = fmaf(old_[ht][r], sent_l[ht], gd[r]);
        float gm[4];
#pragma unroll
        for (int r = 0; r < 4; ++r) {
            gd[r] += __shfl_xor(gd[r], 1);
            gd[r] += __shfl_xor(gd[r], 2);
            gd[r] += __shfl_xor(gd[r], 4);
            gd[r] += __shfl_xor(gd[r], 8);
            float g = 1.f / (1.f + __expf(-(gd[r] + ks_l[r])));
            gm[r] = g * mv;
            if (col == 0)
                out[gbase + (size_t)t * M * B + (size_t)(m0 + rowl + r) * B + b] = g;
        }

        // ---- update + PReLU + L2-normalize (wave-local) ----
        float nsq[4] = {0.f, 0.f, 0.f, 0.f};
#pragma unroll
        for (int ht = 0; ht < 16; ++ht)
#pragma unroll
            for (int r = 0; r < 4; ++r) {
                float x = acc[ht][r] + sw_l[ht];          // mem@U + KC + SW
                float c = (x < 0.f) ? pa_l[ht] * x : x;   // PReLU
                float n = fmaf(gm[r], c, old_[ht][r]);
                acc[ht][r] = n;
                nsq[r] = fmaf(n, n, nsq[r]);
            }
        float scale[4];
#pragma unroll
        for (int r = 0; r < 4; ++r) {
            nsq[r] += __shfl_xor(nsq[r], 1);
            nsq[r] += __shfl_xor(nsq[r], 2);
            nsq[r] += __shfl_xor(nsq[r], 4);
            nsq[r] += __shfl_xor(nsq[r], 8);
            scale[r] = 1.f / fmaxf(sqrtf(nsq[r]), 1e-12f);
        }
#pragma unroll
        for (int ht = 0; ht < 16; ++ht)
#pragma unroll
            for (int r = 0; r < 4; ++r) {
                float v = acc[ht][r] * scale[r];
                old_[ht][r] = v;
                Ap[(rowl + r) * 268 + ht * 16 + col] = packbf(v);
            }
        // next iteration's frag reads are same-wave; lgkmcnt ordering suffices (no barrier)
    }

    // ---- final memory out [M,B,H], exact f32 from registers ----
#pragma unroll
    for (int ht = 0; ht < 16; ++ht)
#pragma unroll
        for (int r = 0; r < 4; ++r)
            out[((size_t)(m0 + rowl + r) * B + b) * Hd + ht * 16 + col] = old_[ht][r];
}

extern "C" void kernel_launch(void* const* d_in, const int* in_sizes, int n_in,
                              void* d_out, int out_size, void* d_ws, size_t ws_size,
                              hipStream_t stream) {
    const float* stories = (const float*)d_in[0];
    const float* mask    = (const float*)d_in[1];
    const float* keys    = (const float*)d_in[2];
    const float* U       = (const float*)d_in[3];
    const float* W       = (const float*)d_in[4];
    const float* V       = (const float*)d_in[5];
    const float* prelu_a = (const float*)d_in[6];
    float* out = (float*)d_out;

    // workspace carve-up (~84.3 MB total)
    float* SW = (float*)d_ws;                        // 16,777,216 f32
    float* KS = SW + (size_t)16777216;               //  4,194,304 f32
    float* KC = KS + (size_t)4194304;                //     16,384 f32
    unsigned short* UBhi = (unsigned short*)(KC + 16384);
    unsigned short* UBlo = UBhi + 65536;
    unsigned short* KChi = UBlo + 65536;
    unsigned short* KClo = KChi + 32768;

    k_sw  <<<dim3(2048),  dim3(256), 0, stream>>>(stories, W, SW);
    k_ks  <<<dim3(65536), dim3(256), 0, stream>>>(stories, keys, KS);
    k_kc  <<<dim3(64),    dim3(256), 0, stream>>>(keys, V, KC);
    k_frag<<<dim3(256),   dim3(256), 0, stream>>>(U, KC, UBhi, UBlo, KChi, KClo);
    dynmem_main<<<dim3(2048), dim3(64), 0, stream>>>(stories, mask, keys, prelu_a,
                                                     SW, KS, UBhi, UBlo, KChi, KClo, out);
}

// Round 3
// 6104.291 us; speedup vs baseline: 1.6272x; 1.0203x over previous
//
#include <hip/hip_runtime.h>
#include <math.h>

// Problem constants (fixed by reference)
constexpr int T  = 128;
constexpr int B  = 512;
constexpr int Hd = 256;
constexpr int M  = 64;
constexpr int RS = 268;   // A-tile row stride in u32 (pad 256->268: frag b128 reads ~2-way max)

// ---- MFMA frag types (gfx950 mfma_f32_16x16x32_f16: A/B = 8 f16, C/D = 4 f32) ----
typedef __attribute__((ext_vector_type(8))) _Float16     half8;
typedef __attribute__((ext_vector_type(4))) float        f32x4;
typedef __attribute__((ext_vector_type(4))) unsigned int u32x4;

union FragA { u32x4 u; half8 h; };

// f16 2-term split: v ~= hi + lo (22 mantissa bits total ~ f32). Packed (hi<<16)|lo.
__device__ __forceinline__ unsigned int packh(float v) {
    _Float16 h = (_Float16)v;                 // RNE
    _Float16 l = (_Float16)(v - (float)h);
    unsigned short hu = __builtin_bit_cast(unsigned short, h);
    unsigned short lu = __builtin_bit_cast(unsigned short, l);
    return ((unsigned int)hu << 16) | (unsigned int)lu;
}

// ---------------- prep kernels ----------------

// KC[m][h] = keys[m] @ V[:,h]  (f32, tiny)
__global__ __launch_bounds__(256) void k_kc(const float* __restrict__ keys,
                                            const float* __restrict__ V,
                                            float* __restrict__ KCo) {
    const int m = blockIdx.x, h = threadIdx.x;
    float a = 0.f;
#pragma unroll 4
    for (int k = 0; k < 256; ++k) a = fmaf(keys[m * 256 + k], V[k * 256 + h], a);
    KCo[m * 256 + h] = a;
}

// U -> f16 B-fragments. UBf[kt(8)][ht(16)][lane(64)][j(8)]: k=kt*32+(l>>4)*8+j, h=ht*16+(l&15)
__global__ __launch_bounds__(256) void k_fragU(const float* __restrict__ U,
                                               _Float16* __restrict__ UBf) {
    const int idx = blockIdx.x * 256 + threadIdx.x;   // [0, 65536)
    const int j = idx & 7, l = (idx >> 3) & 63, ht = (idx >> 9) & 15, kt = idx >> 13;
    const int q = l >> 4, n = l & 15;
    UBf[idx] = (_Float16)U[(kt * 32 + q * 8 + j) * 256 + ht * 16 + n];
}

// [W | keys^T] -> f16 B-fragments for the SW/KS prep GEMM.
// WBf[kt(8)][ht(20)][lane][j]: ht<16 -> W[k][ht*16+n]; ht>=16 -> keys[(ht-16)*16+n][k]
__global__ __launch_bounds__(256) void k_fragW(const float* __restrict__ W,
                                               const float* __restrict__ keys,
                                               _Float16* __restrict__ WBf) {
    const int idx = blockIdx.x * 256 + threadIdx.x;   // [0, 81920)
    const int j = idx & 7, l = (idx >> 3) & 63;
    const int ht = (idx >> 9) % 20, kt = idx / (512 * 20);
    const int q = l >> 4, n = l & 15;
    const int k = kt * 32 + q * 8 + j;
    float v = (ht < 16) ? W[k * 256 + ht * 16 + n]
                        : keys[((ht - 16) * 16 + n) * 256 + k];
    WBf[idx] = (_Float16)v;
}

// SW[tb][h] = stories[tb]@W  and  KS[tb][m] = stories[tb].keys[m], via one f16 MFMA GEMM.
// One wave per 16-row tile (4096 tiles). A = stories rows, f16x2 split from global.
__global__ __launch_bounds__(256, 4) void k_swks(const float* __restrict__ S,
                                                 const _Float16* __restrict__ WBf,
                                                 float* __restrict__ SWo,
                                                 float* __restrict__ KSo) {
    const int tid = threadIdx.x, w = tid >> 6, l = tid & 63;
    const int col = l & 15, q = l >> 4;
    const size_t tb0 = ((size_t)blockIdx.x * 4 + w) * 16;

    f32x4 acc[20];
#pragma unroll
    for (int ht = 0; ht < 20; ++ht) acc[ht] = (f32x4)(0.f);

#pragma unroll
    for (int kt = 0; kt < 8; ++kt) {
        const float* ar = S + (tb0 + col) * 256 + kt * 32 + q * 8;
        f32x4 a0 = *(const f32x4*)ar;
        f32x4 a1 = *(const f32x4*)(ar + 4);
        FragA ah, al;
#pragma unroll
        for (int j = 0; j < 4; ++j) {
            _Float16 h0 = (_Float16)a0[j];
            ah.h[j] = h0; al.h[j] = (_Float16)(a0[j] - (float)h0);
            _Float16 h1 = (_Float16)a1[j];
            ah.h[4 + j] = h1; al.h[4 + j] = (_Float16)(a1[j] - (float)h1);
        }
        const _Float16* bp = WBf + ((size_t)kt * 20 * 64 + l) * 8;
#pragma unroll
        for (int ht = 0; ht < 20; ++ht) {
            FragA fb; fb.u = *(const u32x4*)(bp + ht * 512);
            acc[ht] = __builtin_amdgcn_mfma_f32_16x16x32_f16(ah.h, fb.h, acc[ht], 0, 0, 0);
            acc[ht] = __builtin_amdgcn_mfma_f32_16x16x32_f16(al.h, fb.h, acc[ht], 0, 0, 0);
        }
    }
#pragma unroll
    for (int ht = 0; ht < 20; ++ht)
#pragma unroll
        for (int r = 0; r < 4; ++r) {
            size_t tbr = tb0 + q * 4 + r;             // C row = (lane>>4)*4 + reg
            if (ht < 16) SWo[tbr * 256 + ht * 16 + col] = acc[ht][r];
            else         KSo[tbr * 64 + (ht - 16) * 16 + col] = acc[ht][r];
        }
}

// ---------------- main recurrent kernel ----------------
// WG = 4 waves per (b, 16-m tile); wave w owns h in [w*64, w*64+64) (4 ht tiles).
// Grid 2048 WGs x 256 thr = 8192 waves (vs 2048 last round). State f32 in registers
// (each wave its h-slice); LDS A-tile holds packed f16 hi|lo of the full 16x256 state.
// 2 barriers/step: norm uses ||old+G*c||^2 = Soo + 2G*Soc + G^2*Scc so all partials
// are reducible before G is known.
__global__ __launch_bounds__(256, 4)
void dynmem_main(const float* __restrict__ stories, const float* __restrict__ mask,
                 const float* __restrict__ keys, const float* __restrict__ prelu_a,
                 const float* __restrict__ SW, const float* __restrict__ KS,
                 const float* __restrict__ KC, const _Float16* __restrict__ UBf,
                 float* __restrict__ out) {
    __shared__ __align__(16) unsigned int Ap[16 * RS];
    __shared__ __align__(16) float part[4][16][4];   // [wave][row][gate,Soo,Soc,Scc]

    const int tid = threadIdx.x;
    const int w   = tid >> 6, l = tid & 63;
    const int col = l & 15, q = l >> 4;
    const int rowl = q * 4;                  // C rows rowl..rowl+3
    const int htb  = w * 4;                  // this wave's 4 ht tiles
    const int b  = blockIdx.x >> 2;
    const int mt = blockIdx.x & 3;
    const int m0 = mt * 16;

    // ---- t-invariant preloads ----
    float pa_l[4], sentc[4];
    float old_[4][4], kc_l[4][4];            // [hti][r]: m=m0+rowl+r, h=(htb+hti)*16+col
#pragma unroll
    for (int hti = 0; hti < 4; ++hti) {
        const int h = (htb + hti) * 16 + col;
        pa_l[hti] = prelu_a[h];
#pragma unroll
        for (int r = 0; r < 4; ++r) {
            old_[hti][r] = keys[(m0 + rowl + r) * Hd + h];
            kc_l[hti][r] = KC[(m0 + rowl + r) * Hd + h];
        }
    }
    // init A-tile = keys (unnormalized per reference)
#pragma unroll
    for (int hti = 0; hti < 4; ++hti)
#pragma unroll
        for (int r = 0; r < 4; ++r)
            Ap[(rowl + r) * RS + (htb + hti) * 16 + col] = packh(old_[hti][r]);
    __syncthreads();

    const size_t gbase = (size_t)M * B * Hd;

    for (int t = 0; t < T; ++t) {
        const size_t tb = (size_t)t * B + b;
        const float mv = mask[t * B + b];
        float sent_l[4], sw_l[4], ks_l[4];
#pragma unroll
        for (int hti = 0; hti < 4; ++hti) {
            const int h = (htb + hti) * 16 + col;
            sent_l[hti] = stories[tb * Hd + h];
            sw_l[hti]   = SW[tb * Hd + h];
        }
#pragma unroll
        for (int r = 0; r < 4; ++r) ks_l[r] = KS[tb * 64 + m0 + rowl + r];

        // ---- MFMA: acc[hti] = state @ U (f16 hi+lo A, f16 B) ----
        f32x4 acc[4];
#pragma unroll
        for (int hti = 0; hti < 4; ++hti) acc[hti] = (f32x4)(0.f);

#pragma unroll
        for (int kt = 0; kt < 8; ++kt) {
            const u32x4 p01 = *(const u32x4*)(Ap + col * RS + kt * 32 + q * 8);
            const u32x4 p23 = *(const u32x4*)(Ap + col * RS + kt * 32 + q * 8 + 4);
            FragA ah, al;
            ah.u[0] = __builtin_amdgcn_perm(p01.y, p01.x, 0x07060302u);
            al.u[0] = __builtin_amdgcn_perm(p01.y, p01.x, 0x05040100u);
            ah.u[1] = __builtin_amdgcn_perm(p01.w, p01.z, 0x07060302u);
            al.u[1] = __builtin_amdgcn_perm(p01.w, p01.z, 0x05040100u);
            ah.u[2] = __builtin_amdgcn_perm(p23.y, p23.x, 0x07060302u);
            al.u[2] = __builtin_amdgcn_perm(p23.y, p23.x, 0x05040100u);
            ah.u[3] = __builtin_amdgcn_perm(p23.w, p23.z, 0x07060302u);
            al.u[3] = __builtin_amdgcn_perm(p23.w, p23.z, 0x05040100u);

            const _Float16* bp = UBf + ((size_t)(kt * 16 + htb) * 64 + l) * 8;
#pragma unroll
            for (int hti = 0; hti < 4; ++hti) {
                FragA fb; fb.u = *(const u32x4*)(bp + hti * 512);
                acc[hti] = __builtin_amdgcn_mfma_f32_16x16x32_f16(ah.h, fb.h, acc[hti], 0, 0, 0);
                acc[hti] = __builtin_amdgcn_mfma_f32_16x16x32_f16(al.h, fb.h, acc[hti], 0, 0, 0);
            }
        }

        // ---- candidate + split-reduction partials (all before G is known) ----
        float gd[4], oo[4], oc[4], cc[4];
#pragma unroll
        for (int r = 0; r < 4; ++r) { gd[r] = 0.f; oo[r] = 0.f; oc[r] = 0.f; cc[r] = 0.f; }
#pragma unroll
        for (int hti = 0; hti < 4; ++hti)
#pragma unroll
            for (int r = 0; r < 4; ++r) {
                float o = old_[hti][r];
                float x = acc[hti][r] + sw_l[hti] + kc_l[hti][r];
                float c = (x < 0.f) ? pa_l[hti] * x : x;    // PReLU
                acc[hti][r] = c;                             // keep candidate
                gd[r] = fmaf(o, sent_l[hti], gd[r]);
                oo[r] = fmaf(o, o, oo[r]);
                oc[r] = fmaf(o, c, oc[r]);
                cc[r] = fmaf(c, c, cc[r]);
            }
        // reduce over the 16 cols (xor 1,2,4,8 stays within this quad's 16 lanes)
#pragma unroll
        for (int r = 0; r < 4; ++r) {
#pragma unroll
            for (int s = 1; s <= 8; s <<= 1) {
                gd[r] += __shfl_xor(gd[r], s);
                oo[r] += __shfl_xor(oo[r], s);
                oc[r] += __shfl_xor(oc[r], s);
                cc[r] += __shfl_xor(cc[r], s);
            }
        }
        if (col == 0) {
#pragma unroll
            for (int r = 0; r < 4; ++r) {
                f32x4 pv = {gd[r], oo[r], oc[r], cc[r]};
                *(f32x4*)part[w][rowl + r] = pv;
            }
        }
        __syncthreads();   // barrier 1: partials ready; all A-tile reads complete

        // ---- gate, norm scale, state update, A-tile refresh ----
        float G[4], scl[4];
#pragma unroll
        for (int r = 0; r < 4; ++r) {
            const int row = rowl + r;
            f32x4 p0 = *(const f32x4*)part[0][row];
            f32x4 p1 = *(const f32x4*)part[1][row];
            f32x4 p2 = *(const f32x4*)part[2][row];
            f32x4 p3 = *(const f32x4*)part[3][row];
            float gsum = p0[0] + p1[0] + p2[0] + p3[0];
            float soo  = p0[1] + p1[1] + p2[1] + p3[1];
            float soc  = p0[2] + p1[2] + p2[2] + p3[2];
            float scc  = p0[3] + p1[3] + p2[3] + p3[3];
            float g  = 1.f / (1.f + __expf(-(gsum + ks_l[r])));
            float Gm = g * mv;
            float nsq = soo + 2.f * Gm * soc + Gm * Gm * scc;
            G[r]  = Gm;
            scl[r] = 1.f / fmaxf(sqrtf(nsq), 1e-12f);
            if (w == 0 && col == 0)
                out[gbase + (size_t)t * M * B + (size_t)(m0 + row) * B + b] = g;
        }
#pragma unroll
        for (int hti = 0; hti < 4; ++hti)
#pragma unroll
            for (int r = 0; r < 4; ++r) {
                float v = fmaf(G[r], acc[hti][r], old_[hti][r]) * scl[r];
                old_[hti][r] = v;
                Ap[(rowl + r) * RS + (htb + hti) * 16 + col] = packh(v);
            }
        __syncthreads();   // barrier 2: A-tile ready for next step
    }

    // ---- final memory out [M,B,H], exact f32 from registers ----
#pragma unroll
    for (int hti = 0; hti < 4; ++hti)
#pragma unroll
        for (int r = 0; r < 4; ++r)
            out[((size_t)(m0 + rowl + r) * B + b) * Hd + (htb + hti) * 16 + col] = old_[hti][r];
}

extern "C" void kernel_launch(void* const* d_in, const int* in_sizes, int n_in,
                              void* d_out, int out_size, void* d_ws, size_t ws_size,
                              hipStream_t stream) {
    const float* stories = (const float*)d_in[0];
    const float* mask    = (const float*)d_in[1];
    const float* keys    = (const float*)d_in[2];
    const float* U       = (const float*)d_in[3];
    const float* W       = (const float*)d_in[4];
    const float* V       = (const float*)d_in[5];
    const float* prelu_a = (const float*)d_in[6];
    float* out = (float*)d_out;

    // workspace carve-up (~80.3 MB)
    float* SW = (float*)d_ws;                          // 16,777,216 f32
    float* KS = SW + (size_t)16777216;                 //  4,194,304 f32
    float* KC = KS + (size_t)4194304;                  //     16,384 f32
    _Float16* UBf = (_Float16*)(KC + 16384);           //     65,536 f16
    _Float16* WBf = UBf + 65536;                       //     81,920 f16

    k_kc   <<<dim3(64),   dim3(256), 0, stream>>>(keys, V, KC);
    k_fragU<<<dim3(256),  dim3(256), 0, stream>>>(U, UBf);
    k_fragW<<<dim3(320),  dim3(256), 0, stream>>>(W, keys, WBf);
    k_swks <<<dim3(1024), dim3(256), 0, stream>>>(stories, WBf, SW, KS);
    dynmem_main<<<dim3(2048), dim3(256), 0, stream>>>(stories, mask, keys, prelu_a,
                                                      SW, KS, KC, UBf, out);
}

// Round 4
// 2242.521 us; speedup vs baseline: 4.4294x; 2.7221x over previous
//
#include <hip/hip_runtime.h>
#include <math.h>

// Problem constants (fixed by reference)
constexpr int T  = 128;
constexpr int B  = 512;
constexpr int Hd = 256;
constexpr int M  = 64;
constexpr int SP = 264;   // A-plane row stride in u16 (rows land 4 banks apart; 2-way max = free)

// ---- MFMA frag types (gfx950 mfma_f32_16x16x32_f16: A/B = 8 f16, C/D = 4 f32) ----
typedef __attribute__((ext_vector_type(8))) _Float16     half8;
typedef __attribute__((ext_vector_type(4))) float        f32x4;
typedef __attribute__((ext_vector_type(4))) unsigned int u32x4;

union FragA { u32x4 u; half8 h; };

// f16 2-term split: v ~= hi + lo (22 mantissa bits total ~ f32).
__device__ __forceinline__ void splith(float v, unsigned short& h, unsigned short& l) {
    _Float16 hf = (_Float16)v;
    _Float16 lf = (_Float16)(v - (float)hf);
    h = __builtin_bit_cast(unsigned short, hf);
    l = __builtin_bit_cast(unsigned short, lf);
}

// ---------------- prep kernels ----------------

// KC[m][h] = keys[m] @ V[:,h]  (f32, tiny)
__global__ __launch_bounds__(256) void k_kc(const float* __restrict__ keys,
                                            const float* __restrict__ V,
                                            float* __restrict__ KCo) {
    const int m = blockIdx.x, h = threadIdx.x;
    float a = 0.f;
#pragma unroll 4
    for (int k = 0; k < 256; ++k) a = fmaf(keys[m * 256 + k], V[k * 256 + h], a);
    KCo[m * 256 + h] = a;
}

// U -> f16 B-fragments. UBf[kt(8)][ht(16)][lane(64)][j(8)]: k=kt*32+(l>>4)*8+j, h=ht*16+(l&15)
__global__ __launch_bounds__(256) void k_fragU(const float* __restrict__ U,
                                               _Float16* __restrict__ UBf) {
    const int idx = blockIdx.x * 256 + threadIdx.x;   // [0, 65536)
    const int j = idx & 7, l = (idx >> 3) & 63, ht = (idx >> 9) & 15, kt = idx >> 13;
    const int q = l >> 4, n = l & 15;
    UBf[idx] = (_Float16)U[(kt * 32 + q * 8 + j) * 256 + ht * 16 + n];
}

// [W | keys^T] -> f16 B-fragments for the SW/KS prep GEMM.
__global__ __launch_bounds__(256) void k_fragW(const float* __restrict__ W,
                                               const float* __restrict__ keys,
                                               _Float16* __restrict__ WBf) {
    const int idx = blockIdx.x * 256 + threadIdx.x;   // [0, 81920)
    const int j = idx & 7, l = (idx >> 3) & 63;
    const int ht = (idx >> 9) % 20, kt = idx / (512 * 20);
    const int q = l >> 4, n = l & 15;
    const int k = kt * 32 + q * 8 + j;
    float v = (ht < 16) ? W[k * 256 + ht * 16 + n]
                        : keys[((ht - 16) * 16 + n) * 256 + k];
    WBf[idx] = (_Float16)v;
}

// SW[tb][h] (f16) = stories[tb]@W  and  KS[tb][m] (f32) = stories[tb].keys[m]
__global__ __launch_bounds__(256, 4) void k_swks(const float* __restrict__ S,
                                                 const _Float16* __restrict__ WBf,
                                                 _Float16* __restrict__ SWo,
                                                 float* __restrict__ KSo) {
    const int tid = threadIdx.x, w = tid >> 6, l = tid & 63;
    const int col = l & 15, q = l >> 4;
    const size_t tb0 = ((size_t)blockIdx.x * 4 + w) * 16;

    f32x4 acc[20];
#pragma unroll
    for (int ht = 0; ht < 20; ++ht) acc[ht] = (f32x4)(0.f);

#pragma unroll
    for (int kt = 0; kt < 8; ++kt) {
        const float* ar = S + (tb0 + col) * 256 + kt * 32 + q * 8;
        f32x4 a0 = *(const f32x4*)ar;
        f32x4 a1 = *(const f32x4*)(ar + 4);
        FragA ah, al;
#pragma unroll
        for (int j = 0; j < 4; ++j) {
            _Float16 h0 = (_Float16)a0[j];
            ah.h[j] = h0; al.h[j] = (_Float16)(a0[j] - (float)h0);
            _Float16 h1 = (_Float16)a1[j];
            ah.h[4 + j] = h1; al.h[4 + j] = (_Float16)(a1[j] - (float)h1);
        }
        const _Float16* bp = WBf + ((size_t)kt * 20 * 64 + l) * 8;
#pragma unroll
        for (int ht = 0; ht < 20; ++ht) {
            FragA fb; fb.u = *(const u32x4*)(bp + ht * 512);
            acc[ht] = __builtin_amdgcn_mfma_f32_16x16x32_f16(ah.h, fb.h, acc[ht], 0, 0, 0);
            acc[ht] = __builtin_amdgcn_mfma_f32_16x16x32_f16(al.h, fb.h, acc[ht], 0, 0, 0);
        }
    }
#pragma unroll
    for (int ht = 0; ht < 20; ++ht)
#pragma unroll
        for (int r = 0; r < 4; ++r) {
            size_t tbr = tb0 + q * 4 + r;
            if (ht < 16) SWo[tbr * 256 + ht * 16 + col] = (_Float16)acc[ht][r];
            else         KSo[tbr * 64 + (ht - 16) * 16 + col] = acc[ht][r];
        }
}

// gates transpose: GT[bg=b*4+mt][t*16+row] -> out[t][mt*16+row][b]
__global__ __launch_bounds__(256) void k_gt(const float* __restrict__ GT,
                                            float* __restrict__ out) {
    __shared__ float tile[64][65];
    const int mt = blockIdx.x & 3;
    const int bT = (blockIdx.x >> 2) & 7;
    const int trT = blockIdx.x >> 5;
    const int tx = threadIdx.x & 63, ty = threadIdx.x >> 6;
    const int b0 = bT * 64, tr0 = trT * 64;
#pragma unroll 4
    for (int i = 0; i < 16; ++i) {
        int r = i * 4 + ty;
        tile[r][tx] = GT[((size_t)(b0 + r) * 4 + mt) * 2048 + tr0 + tx];
    }
    __syncthreads();
    const size_t gbase = (size_t)M * B * Hd;
#pragma unroll 4
    for (int i = 0; i < 16; ++i) {
        int r = i * 4 + ty;
        int tr = tr0 + r;
        out[gbase + (size_t)(tr >> 4) * (M * B) + (size_t)(mt * 16 + (tr & 15)) * B + b0 + tx]
            = tile[tx][r];
    }
}

// ---------------- main recurrent kernel ----------------
// WG = (b, 16-m tile), 4 waves; wave w owns h in [w*64, w*64+64) (4 ht tiles).
// KEY CHANGE vs r3: the wave's U B-fragments (8 kt x 4 ht = 128 VGPRs) are loaded ONCE
// and stay in registers for all 128 steps -> per-step global traffic ~0 (was 21 GB total).
// A-state in two f16 LDS planes (hi/lo, u16, stride 264) -> ds_read_b128 gives the A-frag
// directly, no unpack perms. Norm partial Sum(old^2)==1 after first normalize (t=0 uses
// precomputed ||keys||^2), so only 3 reduced quantities; cross-wave finalize via bpermute.
__global__ __launch_bounds__(256, 2)
void dynmem_main(const float* __restrict__ stories, const float* __restrict__ mask,
                 const float* __restrict__ keys, const float* __restrict__ prelu_a,
                 const _Float16* __restrict__ SW, const float* __restrict__ KS,
                 const float* __restrict__ KC, const _Float16* __restrict__ UBf,
                 float* __restrict__ GT, float* __restrict__ out) {
    __shared__ __align__(16) unsigned short Aph[16 * SP];
    __shared__ __align__(16) unsigned short Apl[16 * SP];
    __shared__ __align__(16) float part[4][16][4];   // [wave][row][gd,oc,cc,pad]

    const int tid = threadIdx.x;
    const int w = tid >> 6, l = tid & 63;
    const int col = l & 15, q = l >> 4;
    const int rowl = q * 4;                  // C rows rowl..rowl+3
    const int htb  = w * 4;                  // this wave's 4 ht tiles
    const int b  = blockIdx.x >> 2;
    const int mt = blockIdx.x & 3;
    const int m0 = mt * 16;
    const int bg = blockIdx.x;

    // ---- t-invariant: U B-fragments resident in VGPRs ----
    FragA bfr[8][4];
#pragma unroll
    for (int kt = 0; kt < 8; ++kt)
#pragma unroll
        for (int hti = 0; hti < 4; ++hti)
            bfr[kt][hti].u = *(const u32x4*)(UBf + ((size_t)(kt * 16 + htb + hti) * 64 + l) * 8);

    float pa_l[4], old_[4][4], kc_l[4][4];
#pragma unroll
    for (int hti = 0; hti < 4; ++hti) {
        const int h = (htb + hti) * 16 + col;
        pa_l[hti] = prelu_a[h];
#pragma unroll
        for (int r = 0; r < 4; ++r) {
            old_[hti][r] = keys[(m0 + rowl + r) * Hd + h];
            kc_l[hti][r] = KC[(m0 + rowl + r) * Hd + h];
        }
    }
    // okk = ||keys[m0+col]||^2 (for t=0 norm; afterwards ||old||==1)
    float okk = 0.f;
    {
        const float* kr = keys + (m0 + col) * Hd;
#pragma unroll 4
        for (int k = 0; k < 256; k += 4) {
            f32x4 kv = *(const f32x4*)(kr + k);
            okk = fmaf(kv[0], kv[0], okk); okk = fmaf(kv[1], kv[1], okk);
            okk = fmaf(kv[2], kv[2], okk); okk = fmaf(kv[3], kv[3], okk);
        }
    }
    // init A-planes = keys (unnormalized per reference)
#pragma unroll
    for (int hti = 0; hti < 4; ++hti)
#pragma unroll
        for (int r = 0; r < 4; ++r) {
            unsigned short hh, ll;
            splith(old_[hti][r], hh, ll);
            Aph[(rowl + r) * SP + (htb + hti) * 16 + col] = hh;
            Apl[(rowl + r) * SP + (htb + hti) * 16 + col] = ll;
        }
    __syncthreads();

    for (int t = 0; t < T; ++t) {
        const size_t tb = (size_t)t * B + b;
        const float mv = mask[t * B + b];
        const float ksR = KS[tb * 64 + m0 + col];     // this lane's row = col in phase B
        float sent_l[4], sw_l[4];
#pragma unroll
        for (int hti = 0; hti < 4; ++hti) {
            const int h = (htb + hti) * 16 + col;
            sent_l[hti] = stories[tb * Hd + h];
            sw_l[hti]   = (float)SW[tb * Hd + h];
        }

        // ---- MFMA: acc[hti] = state @ U (A = hi+lo planes, B from registers) ----
        f32x4 acc[4];
#pragma unroll
        for (int hti = 0; hti < 4; ++hti) acc[hti] = (f32x4)(0.f);

#pragma unroll
        for (int kt = 0; kt < 8; ++kt) {
            const half8 ah = *(const half8*)(const void*)(Aph + col * SP + kt * 32 + q * 8);
            const half8 al = *(const half8*)(const void*)(Apl + col * SP + kt * 32 + q * 8);
#pragma unroll
            for (int hti = 0; hti < 4; ++hti)
                acc[hti] = __builtin_amdgcn_mfma_f32_16x16x32_f16(ah, bfr[kt][hti].h, acc[hti], 0, 0, 0);
#pragma unroll
            for (int hti = 0; hti < 4; ++hti)
                acc[hti] = __builtin_amdgcn_mfma_f32_16x16x32_f16(al, bfr[kt][hti].h, acc[hti], 0, 0, 0);
        }

        // ---- candidate + partials (gd = old.sent, oc = old.cand, cc = cand.cand) ----
        float gd[4], oc[4], cc[4];
#pragma unroll
        for (int r = 0; r < 4; ++r) { gd[r] = 0.f; oc[r] = 0.f; cc[r] = 0.f; }
#pragma unroll
        for (int hti = 0; hti < 4; ++hti)
#pragma unroll
            for (int r = 0; r < 4; ++r) {
                float o = old_[hti][r];
                float x = acc[hti][r] + sw_l[hti] + kc_l[hti][r];
                float c = (x < 0.f) ? pa_l[hti] * x : x;    // PReLU
                acc[hti][r] = c;                             // keep candidate
                gd[r] = fmaf(o, sent_l[hti], gd[r]);
                oc[r] = fmaf(o, c, oc[r]);
                cc[r] = fmaf(c, c, cc[r]);
            }
#pragma unroll
        for (int r = 0; r < 4; ++r)
#pragma unroll
            for (int s = 1; s <= 8; s <<= 1) {
                gd[r] += __shfl_xor(gd[r], s);
                oc[r] += __shfl_xor(oc[r], s);
                cc[r] += __shfl_xor(cc[r], s);
            }
        if (col == 0) {
#pragma unroll
            for (int r = 0; r < 4; ++r) {
                f32x4 pv = {gd[r], oc[r], cc[r], 0.f};
                *(f32x4*)part[w][rowl + r] = pv;
            }
        }
        __syncthreads();   // barrier 1: partials ready; all A-plane reads complete

        // ---- phase B (done redundantly per wave): lane handles row=col, comp=q ----
        float S = part[0][col][q] + part[1][col][q] + part[2][col][q] + part[3][col][q];
        float gdS = __shfl(S, col);
        float ocS = __shfl(S, col + 16);
        float ccS = __shfl(S, col + 32);
        float g   = 1.f / (1.f + __expf(-(gdS + ksR)));
        float Gm  = g * mv;
        float ooc = (t == 0) ? okk : 1.0f;
        float nsq = fmaf(Gm, fmaf(Gm, ccS, 2.f * ocS), ooc);
        float scl = 1.f / fmaxf(sqrtf(nsq), 1e-12f);
        if (tid < 16) GT[(size_t)bg * 2048 + t * 16 + tid] = g;

        float Gr[4], sr[4];
#pragma unroll
        for (int r = 0; r < 4; ++r) {
            Gr[r] = __shfl(Gm, rowl + r);
            sr[r] = __shfl(scl, rowl + r);
        }

        // ---- state update + A-plane refresh ----
#pragma unroll
        for (int hti = 0; hti < 4; ++hti)
#pragma unroll
            for (int r = 0; r < 4; ++r) {
                float n = fmaf(Gr[r], acc[hti][r], old_[hti][r]) * sr[r];
                old_[hti][r] = n;
                unsigned short hh, ll;
                splith(n, hh, ll);
                Aph[(rowl + r) * SP + (htb + hti) * 16 + col] = hh;
                Apl[(rowl + r) * SP + (htb + hti) * 16 + col] = ll;
            }
        __syncthreads();   // barrier 2: A-planes ready for next step
    }

    // ---- final memory out [M,B,H], exact f32 from registers ----
#pragma unroll
    for (int hti = 0; hti < 4; ++hti)
#pragma unroll
        for (int r = 0; r < 4; ++r)
            out[((size_t)(m0 + rowl + r) * B + b) * Hd + (htb + hti) * 16 + col] = old_[hti][r];
}

extern "C" void kernel_launch(void* const* d_in, const int* in_sizes, int n_in,
                              void* d_out, int out_size, void* d_ws, size_t ws_size,
                              hipStream_t stream) {
    const float* stories = (const float*)d_in[0];
    const float* mask    = (const float*)d_in[1];
    const float* keys    = (const float*)d_in[2];
    const float* U       = (const float*)d_in[3];
    const float* W       = (const float*)d_in[4];
    const float* V       = (const float*)d_in[5];
    const float* prelu_a = (const float*)d_in[6];
    float* out = (float*)d_out;

    // workspace carve-up (~67.5 MB)
    _Float16* SW  = (_Float16*)d_ws;                   // 16,777,216 f16 (33.55 MB)
    float*    KS  = (float*)(SW + 16777216);           //  4,194,304 f32 (16.78 MB)
    float*    KC  = KS + 4194304;                      //     16,384 f32
    _Float16* UBf = (_Float16*)(KC + 16384);           //     65,536 f16
    _Float16* WBf = UBf + 65536;                       //     81,920 f16
    float*    GT  = (float*)(WBf + 81920);             //  4,194,304 f32 (16.78 MB)

    k_kc   <<<dim3(64),   dim3(256), 0, stream>>>(keys, V, KC);
    k_fragU<<<dim3(256),  dim3(256), 0, stream>>>(U, UBf);
    k_fragW<<<dim3(320),  dim3(256), 0, stream>>>(W, keys, WBf);
    k_swks <<<dim3(1024), dim3(256), 0, stream>>>(stories, WBf, SW, KS);
    dynmem_main<<<dim3(2048), dim3(256), 0, stream>>>(stories, mask, keys, prelu_a,
                                                      SW, KS, KC, UBf, GT, out);
    k_gt   <<<dim3(1024), dim3(256), 0, stream>>>(GT, out);
}